// Round 7
// baseline (821.628 us; speedup 1.0000x reference)
//
#include <hip/hip_runtime.h>
#include <hip/hip_bf16.h>
#include <math.h>

typedef __hip_bfloat16 bf16;
typedef unsigned short ushort;
typedef __attribute__((ext_vector_type(8))) short short8;
typedef __attribute__((ext_vector_type(4))) float float4v;

#define BATCH 64
#define NPIX 596
#define CH 34
#define PC 256

static __device__ __forceinline__ ushort f2bu(float v){ bf16 h = __float2bfloat16(v); return *(ushort*)&h; }
static __device__ __forceinline__ float eluf(float x){ return x > 0.f ? x : expm1f(x); }

// ---------------------------------------------------------------------------
// K1: conv1+relu -> conv2+relu -> feats (B, 596, 34) f32.
// ---------------------------------------------------------------------------
__global__ __launch_bounds__(256) void k_conv_feats(
    const float* __restrict__ x,
    const float* __restrict__ w1, const float* __restrict__ b1,
    const float* __restrict__ w2, const float* __restrict__ b2,
    float* __restrict__ feats)
{
  __shared__ float sw1[256];
  __shared__ float sb1[16];
  __shared__ float sw2[2048];
  __shared__ float sb2[32];
  __shared__ float h1[16*150*5];
  const int b = blockIdx.x, t = threadIdx.x;
  const float* xb = x + (size_t)b * 4*151*6;

  sw1[t]=w1[t];
  if (t<16) sb1[t]=b1[t];
  for (int i=t;i<2048;i+=256) sw2[i]=w2[i];
  if (t<32) sb2[t]=b2[t];
  __syncthreads();

  for (int i=t;i<12000;i+=256){
    int oc = i/750, rem = i-oc*750;
    int r = rem/5, cc = rem-(rem/5)*5;
    float acc = sb1[oc];
    #pragma unroll
    for (int ic=0;ic<4;ic++){
      const float* xp = xb + ic*906 + r*6 + cc;
      const float* wp = sw1 + oc*16 + ic*4;
      acc += xp[0]*wp[0] + xp[1]*wp[1] + xp[6]*wp[2] + xp[7]*wp[3];
    }
    h1[i] = fmaxf(acc, 0.f);
  }
  __syncthreads();

  float* fb = feats + (size_t)b*NPIX*CH;
  for (int i=t;i<32*NPIX;i+=256){
    int oc = i/NPIX, p = i - oc*NPIX;
    int r = p>>2, cc = p&3;
    float acc = sb2[oc];
    #pragma unroll
    for (int ic=0;ic<16;ic++){
      const float* hp = h1 + ic*750 + r*5 + cc;
      const float* wp = sw2 + oc*64 + ic*4;
      acc += hp[0]*wp[0] + hp[1]*wp[1] + hp[5]*wp[2] + hp[6]*wp[3];
    }
    fb[p*CH+oc] = fmaxf(acc, 0.f);
  }
  for (int p=t;p<NPIX;p+=256){
    fb[p*CH+32] = (float)(p&3)*0.25f;
    fb[p*CH+33] = (float)(p>>2)*(1.0f/149.0f);
  }
}

// ---------------------------------------------------------------------------
// K_prep: pack weights in MFMA B-fragment order, bf16. Also zeroes stats.
// 1KB per (tile, kchunk): lane l=(quad,ln) holds 8 halves
// B[k = kchunk*32 + quad*8 + j][n = tile*16 + ln].
// ---------------------------------------------------------------------------
__global__ __launch_bounds__(256) void k_prep(
    const float* __restrict__ aw, const float* __restrict__ qw, const float* __restrict__ kw,
    const float* __restrict__ l1w,
    ushort* __restrict__ alinP, ushort* __restrict__ WqkP, ushort* __restrict__ w1T,
    float* __restrict__ statsZ)
{
  if (blockIdx.x == 0){
    statsZ[threadIdx.x] = 0.f;
    statsZ[threadIdx.x + 256] = 0.f;
  }
  int s = blockIdx.x*256 + threadIdx.x;
  if (s < 48640){
    int tile = s/(19*64), rem = s%(19*64);
    int kk = rem>>6, l = rem&63;
    int n = tile*16 + (l&15);
    int c0 = kk*32 + (l>>4)*8;
    ushort out[8];
    #pragma unroll
    for (int i=0;i<8;i++){
      int c = c0+i;
      out[i] = (n<NPIX && c<NPIX) ? f2bu(aw[(size_t)c*NPIX + n]) : 0;
    }
    *(short8*)(alinP + (size_t)s*8) = *(short8*)out;
  } else if (s < 58880){
    int s2 = s - 48640;
    int tile = s2/(4*64), rem = s2%(4*64);
    int kk = rem>>6, l = rem&63;
    int n = tile*16 + (l&15);
    int k0 = kk*32 + (l>>4)*8;
    ushort out[8];
    #pragma unroll
    for (int i=0;i<8;i++){
      int k = k0+i;
      float v = 0.f;
      if (n<NPIX) v = (k<64) ? qw[(size_t)k*NPIX + n] : kw[(size_t)(k-64)*NPIX + n];
      out[i] = (n<NPIX) ? f2bu(v) : 0;
    }
    *(short8*)(WqkP + (size_t)s2*8) = *(short8*)out;
  } else if (s < 60928){
    int s3 = s - 58880;
    int n = s3>>5, e0 = (s3&31)*8;
    ushort out[8];
    #pragma unroll
    for (int i=0;i<8;i++) out[i] = f2bu(l1w[(size_t)(e0+i)*64 + n]);
    *(short8*)(w1T + (size_t)s3*8) = *(short8*)out;
  }
}

// ---------------------------------------------------------------------------
// K_vt: pack V into fragment order. Per bh: VP slot g=(w*19+kk)*64+l holds
// V[j = kk*32 + quad*8 + jj][d = w*16 + ln].  4864 short8 per bh.
// ---------------------------------------------------------------------------
__global__ __launch_bounds__(256) void k_vt(
    const ushort* __restrict__ Vb, ushort* __restrict__ VP)
{
  extern __shared__ ushort vt[];     // 64 x 608
  const int bh = blockIdx.x, t = threadIdx.x;
  const ushort* Vp = Vb + (size_t)bh*NPIX*64;
  for (int g=t; g<4768; g+=256){
    int p = g>>3, d0 = (g&7)*8;
    short8 vv = *(const short8*)(Vp + (size_t)p*64 + d0);
    #pragma unroll
    for (int i=0;i<8;i++) vt[(d0+i)*608 + p] = ((ushort*)&vv)[i];
  }
  __syncthreads();
  for (int g=t; g<4864; g+=256){
    int w2 = g/1216, rem = g%1216;
    int kk = rem>>6, l = rem&63;
    int d = w2*16 + (l&15);
    int j0 = kk*32 + (l>>4)*8;
    ushort out[8];
    #pragma unroll
    for (int i=0;i<8;i++){
      int j = j0+i;
      out[i] = (j<NPIX) ? vt[d*608 + j] : 0;
    }
    *(short8*)(VP + ((size_t)bh*4864 + g)*8) = *(short8*)out;
  }
}

// ---------------------------------------------------------------------------
// P1: proj stats. grid (4 ptiles, 64 b, 3 which). atomic partial sums.
// ---------------------------------------------------------------------------
__global__ __launch_bounds__(256) void k_proj_p1(
    const float* __restrict__ feats,
    const float* __restrict__ kpw, const float* __restrict__ kpb,
    const float* __restrict__ qpw, const float* __restrict__ qpb,
    const float* __restrict__ vpw, const float* __restrict__ vpb,
    float* __restrict__ statsP)
{
  __shared__ float sw[CH*PC];
  __shared__ float sb[PC];
  __shared__ float sf[149*CH];
  __shared__ float red[8];
  const int pt = blockIdx.x, b = blockIdx.y, which = blockIdx.z, t = threadIdx.x;
  const float* W  = which==0 ? kpw : which==1 ? qpw : vpw;
  const float* Bv = which==0 ? kpb : which==1 ? qpb : vpb;
  for (int i=t;i<CH*PC;i+=256) sw[i]=W[i];
  sb[t]=Bv[t];
  const float* fb = feats + ((size_t)b*NPIX + pt*149)*CH;
  for (int i=t;i<149*CH;i+=256) sf[i]=fb[i];
  __syncthreads();
  float s=0.f, s2=0.f;
  for (int p=0;p<149;p++){
    float acc = sb[t];
    const float* fr = sf + p*CH;
    #pragma unroll
    for (int e=0;e<CH;e++) acc += fr[e]*sw[e*PC+t];
    s += acc; s2 += acc*acc;
  }
  #pragma unroll
  for (int o=32;o>0;o>>=1){ s += __shfl_down(s,o); s2 += __shfl_down(s2,o); }
  if ((t&63)==0){ red[t>>6]=s; red[4+(t>>6)]=s2; }
  __syncthreads();
  if (t==0){
    atomicAdd(&statsP[(which*64+b)*2],   red[0]+red[1]+red[2]+red[3]);
    atomicAdd(&statsP[(which*64+b)*2+1], red[4]+red[5]+red[6]+red[7]);
  }
}

// ---------------------------------------------------------------------------
// P2: proj recompute + LN + affine -> bf16 (B,4,596,64).
// ---------------------------------------------------------------------------
__global__ __launch_bounds__(256) void k_proj_p2(
    const float* __restrict__ feats,
    const float* __restrict__ kpw, const float* __restrict__ kpb,
    const float* __restrict__ qpw, const float* __restrict__ qpb,
    const float* __restrict__ vpw, const float* __restrict__ vpb,
    const float* __restrict__ kg, const float* __restrict__ kb_,
    const float* __restrict__ qg, const float* __restrict__ qb_,
    const float* __restrict__ vg, const float* __restrict__ vb_,
    const float* __restrict__ statsP,
    ushort* __restrict__ Kb, ushort* __restrict__ Qb, ushort* __restrict__ Vb)
{
  __shared__ float sw[CH*PC];
  __shared__ float sb[PC];
  __shared__ float sf[149*CH];
  const int pt = blockIdx.x, b = blockIdx.y, which = blockIdx.z, t = threadIdx.x;
  const float* W  = which==0 ? kpw : which==1 ? qpw : vpw;
  const float* Bv = which==0 ? kpb : which==1 ? qpb : vpb;
  const float* G  = which==0 ? kg  : which==1 ? qg  : vg;
  const float* Be = which==0 ? kb_ : which==1 ? qb_ : vb_;
  ushort* out     = which==0 ? Kb  : which==1 ? Qb  : Vb;
  for (int i=t;i<CH*PC;i+=256) sw[i]=W[i];
  sb[t]=Bv[t];
  const float* fb = feats + ((size_t)b*NPIX + pt*149)*CH;
  for (int i=t;i<149*CH;i+=256) sf[i]=fb[i];
  __syncthreads();
  const float n = (float)(NPIX*PC);
  const float S  = statsP[(which*64+b)*2];
  const float S2 = statsP[(which*64+b)*2+1];
  const float mu = S/n;
  const float rs = rsqrtf(S2/n - mu*mu + 1e-5f);
  const int h = t>>6, d = t&63;
  for (int p=0;p<149;p++){
    float acc = sb[t];
    const float* fr = sf + p*CH;
    #pragma unroll
    for (int e=0;e<CH;e++) acc += fr[e]*sw[e*PC+t];
    int pg = pt*149 + p;
    int gi = (h*NPIX+pg)*64 + d;
    float y = (acc-mu)*rs*G[gi] + Be[gi];
    out[((size_t)(b*4+h)*NPIX + pg)*64 + d] = f2bu(y);
  }
}

// ---------------------------------------------------------------------------
// K3: fused MFMA attention. M=128 rows/block, N=640 (40 tiles), 512 threads
// (8 waves, 5 n-tiles x 8 m-tiles each). B-frags stream from global packed
// buffers; A-frags from LDS strip (128x616 bf16). LDS 161,792 B ->
// 1 block/CU, 8 waves. acc 160 f32/thread -> needs 256-reg budget: LB(512,2).
// grid (5 row-strips, 256 bh).
// ---------------------------------------------------------------------------
__global__ __launch_bounds__(512, 2) void k_attn(
    const ushort* __restrict__ Qb, const ushort* __restrict__ Kb,
    const ushort* __restrict__ alinP, const ushort* __restrict__ WqkP,
    const ushort* __restrict__ VP,
    const float* __restrict__ qbias, const float* __restrict__ kbias,
    const float* __restrict__ abias,
    ushort* __restrict__ Ew)
{
  extern __shared__ __align__(16) ushort sm[];
  ushort* strip = sm;                    // 128*616 = 78848 halves
  float*  red   = (float*)(sm + 78848);  // 1024 f32

  const int t = threadIdx.x;
  const int w = t>>6, l = t&63, quad = l>>4, ln = l&15;
  const int rb = blockIdx.x, bh = blockIdx.y;
  const int b = bh>>2, h = bh&3;
  const int row0 = rb*128;
  const ushort* Qp = Qb + (size_t)bh*NPIX*64;
  const ushort* Kp = Kb + (size_t)bh*NPIX*64;

  float4v acc[8][5];
  #pragma unroll
  for (int ms=0;ms<8;ms++)
    #pragma unroll
    for (int i=0;i<5;i++) acc[ms][i] = (float4v){0.f,0.f,0.f,0.f};

  // ---------------- A0 = elu([Q|K] @ Wqk + qb + kb) ----------------
  #pragma unroll
  for (int kk=0;kk<4;kk++){
    short8 aq[8];
    #pragma unroll
    for (int ms=0;ms<8;ms++){
      int r = row0 + ms*16 + ln;
      short8 z = {0,0,0,0,0,0,0,0};
      aq[ms] = (r < NPIX)
        ? *(const short8*)((kk<2 ? Qp : Kp) + (size_t)r*64 + (kk&1)*32 + quad*8) : z;
    }
    #pragma unroll
    for (int i=0;i<5;i++){
      int tile = w + 8*i;
      short8 bf = *(const short8*)(WqkP + ((size_t)(tile*4 + kk)*64 + l)*8);
      #pragma unroll
      for (int ms=0;ms<8;ms++)
        acc[ms][i] = __builtin_amdgcn_mfma_f32_16x16x32_bf16(aq[ms], bf, acc[ms][i], 0,0,0);
    }
  }
  // epilogue: bias + elu -> strip (cols < 608 only)
  #pragma unroll
  for (int i=0;i<5;i++){
    int t0 = w + 8*i;
    if (t0 < 38){
      int col = t0*16 + ln;
      bool cv = col < NPIX;
      float qkb = cv ? (qbias[col] + kbias[col]) : 0.f;
      #pragma unroll
      for (int ms=0;ms<8;ms++)
        #pragma unroll
        for (int r=0;r<4;r++){
          float v = 0.f;
          if (cv){ float xx = acc[ms][i][r] + qkb; v = xx > 0.f ? xx : __expf(xx) - 1.f; }
          strip[(ms*16+quad*4+r)*616 + col] = f2bu(v);
        }
    }
  }
  __syncthreads();

  // ---------------- S = A0 @ alin (no barriers in loop) ----------------
  #pragma unroll
  for (int ms=0;ms<8;ms++)
    #pragma unroll
    for (int i=0;i<5;i++) acc[ms][i] = (float4v){0.f,0.f,0.f,0.f};
  for (int kk=0;kk<19;kk++){
    short8 af[8];
    #pragma unroll
    for (int ms=0;ms<8;ms++)
      af[ms] = *(const short8*)(strip + (ms*16+ln)*616 + kk*32 + quad*8);
    #pragma unroll
    for (int i=0;i<5;i++){
      int tile = w + 8*i;
      short8 bf = *(const short8*)(alinP + ((size_t)(tile*19 + kk)*64 + l)*8);
      #pragma unroll
      for (int ms=0;ms<8;ms++)
        acc[ms][i] = __builtin_amdgcn_mfma_f32_16x16x32_bf16(af[ms], bf, acc[ms][i], 0,0,0);
    }
  }

  // ---------------- softmax (exact, cross-wave over 8 waves) ----------------
  float M_[8][4], sum[8][4];
  #pragma unroll
  for (int ms=0;ms<8;ms++)
    #pragma unroll
    for (int r=0;r<4;r++) M_[ms][r] = -1e30f;
  #pragma unroll
  for (int i=0;i<5;i++){
    int col = (w+8*i)*16 + ln;
    float ab = (col < NPIX) ? abias[col] : 0.f;
    #pragma unroll
    for (int ms=0;ms<8;ms++)
      #pragma unroll
      for (int r=0;r<4;r++){
        float s = (col < NPIX) ? acc[ms][i][r] + ab : -1e30f;
        acc[ms][i][r] = s;
        M_[ms][r] = fmaxf(M_[ms][r], s);
      }
  }
  #pragma unroll
  for (int ms=0;ms<8;ms++)
    #pragma unroll
    for (int r=0;r<4;r++)
      #pragma unroll
      for (int o=8;o>0;o>>=1) M_[ms][r] = fmaxf(M_[ms][r], __shfl_xor(M_[ms][r], o, 16));
  __syncthreads();   // strip reads done; red safe
  if (ln==0){
    #pragma unroll
    for (int ms=0;ms<8;ms++)
      #pragma unroll
      for (int r=0;r<4;r++) red[(ms*16+quad*4+r)*8 + w] = M_[ms][r];
  }
  __syncthreads();
  #pragma unroll
  for (int ms=0;ms<8;ms++)
    #pragma unroll
    for (int r=0;r<4;r++){
      const float* rr = red + (ms*16+quad*4+r)*8;
      float m0 = fmaxf(fmaxf(rr[0],rr[1]), fmaxf(rr[2],rr[3]));
      float m1 = fmaxf(fmaxf(rr[4],rr[5]), fmaxf(rr[6],rr[7]));
      M_[ms][r] = fmaxf(m0, m1);
      sum[ms][r] = 0.f;
    }
  #pragma unroll
  for (int i=0;i<5;i++)
    #pragma unroll
    for (int ms=0;ms<8;ms++)
      #pragma unroll
      for (int r=0;r<4;r++){
        float e = __expf(acc[ms][i][r] - M_[ms][r]);
        acc[ms][i][r] = e;
        sum[ms][r] += e;
      }
  #pragma unroll
  for (int ms=0;ms<8;ms++)
    #pragma unroll
    for (int r=0;r<4;r++)
      #pragma unroll
      for (int o=8;o>0;o>>=1) sum[ms][r] += __shfl_xor(sum[ms][r], o, 16);
  __syncthreads();
  if (ln==0){
    #pragma unroll
    for (int ms=0;ms<8;ms++)
      #pragma unroll
      for (int r=0;r<4;r++) red[(ms*16+quad*4+r)*8 + w] = sum[ms][r];
  }
  __syncthreads();
  #pragma unroll
  for (int ms=0;ms<8;ms++)
    #pragma unroll
    for (int r=0;r<4;r++){
      const float* rr = red + (ms*16+quad*4+r)*8;
      M_[ms][r] = 1.f / (rr[0]+rr[1]+rr[2]+rr[3]+rr[4]+rr[5]+rr[6]+rr[7]);  // inv
    }
  #pragma unroll
  for (int i=0;i<5;i++){
    int t0 = w + 8*i;
    if (t0 < 38){
      int col = t0*16 + ln;
      #pragma unroll
      for (int ms=0;ms<8;ms++)
        #pragma unroll
        for (int r=0;r<4;r++)
          strip[(ms*16+quad*4+r)*616 + col] = f2bu(acc[ms][i][r] * M_[ms][r]);
    }
  }
  __syncthreads();

  // ---------------- E = P @ V  (wave -> d-tile w&3, m-half w>>2) ----------------
  const int dt = w&3, mh = w>>2;
  float4v ve[4];
  #pragma unroll
  for (int ms=0;ms<4;ms++) ve[ms] = (float4v){0.f,0.f,0.f,0.f};
  for (int kk=0;kk<19;kk++){
    short8 bf = *(const short8*)(VP + ((size_t)bh*4864 + (dt*19 + kk)*64 + l)*8);
    #pragma unroll
    for (int ms=0;ms<4;ms++){
      short8 af = *(const short8*)(strip + ((mh*4+ms)*16+ln)*616 + kk*32 + quad*8);
      ve[ms] = __builtin_amdgcn_mfma_f32_16x16x32_bf16(af, bf, ve[ms], 0,0,0);
    }
  }
  __syncthreads();   // all strip reads done
  // stage 128x64 bf16 tile (row stride 72 halves) for coalesced Ew write
  #pragma unroll
  for (int ms=0;ms<4;ms++)
    #pragma unroll
    for (int r=0;r<4;r++)
      strip[((mh*4+ms)*16+quad*4+r)*72 + dt*16 + ln] = f2bu(ve[ms][r]);
  __syncthreads();
  {
    int p = t>>2, seg = t&3;
    int gp = row0 + p;
    if (gp < NPIX){
      short8 v0 = *(const short8*)(strip + p*72 + seg*16);
      short8 v1 = *(const short8*)(strip + p*72 + seg*16 + 8);
      ushort* dst = Ew + ((size_t)b*NPIX + gp)*256 + h*64 + seg*16;
      *(short8*)dst = v0;
      *(short8*)(dst + 8) = v1;
    }
  }
}

// ---------------------------------------------------------------------------
// K4: lin1 via MFMA + relu + per-batch LN stats. grid (10 rowblocks, 64 b).
// ---------------------------------------------------------------------------
__global__ __launch_bounds__(256) void k_lin1(
    const ushort* __restrict__ Ew, const ushort* __restrict__ w1T,
    const float* __restrict__ bias,
    float* __restrict__ F, float* __restrict__ stats)
{
  __shared__ ushort sw1[64*264];
  __shared__ float red[8];
  const int t = threadIdx.x;
  const int w = t>>6, l = t&63, quad = l>>4, ln = l&15;
  const int rb = blockIdx.x, b = blockIdx.y;
  for (int g=t; g<2048; g+=256){
    int row = g>>5, q = g&31;
    *(short8*)(sw1 + row*264 + q*8) = *(const short8*)(w1T + row*256 + q*8);
  }
  __syncthreads();
  float4v acc[4];
  #pragma unroll
  for (int ms=0;ms<4;ms++) acc[ms] = (float4v){0.f,0.f,0.f,0.f};
  #pragma unroll
  for (int kk=0;kk<8;kk++){
    short8 bf = *(const short8*)(sw1 + (w*16+ln)*264 + kk*32 + quad*8);
    #pragma unroll
    for (int ms=0;ms<4;ms++){
      int p = rb*64 + ms*16 + ln;
      size_t rowi = (size_t)b*NPIX + (p < NPIX ? p : 0);
      short8 a = *(const short8*)(Ew + rowi*256 + kk*32 + quad*8);
      acc[ms] = __builtin_amdgcn_mfma_f32_16x16x32_bf16(a, bf, acc[ms], 0,0,0);
    }
  }
  const int col = w*16 + ln;
  const float bc = bias[col];
  float s=0.f, s2=0.f;
  #pragma unroll
  for (int ms=0;ms<4;ms++)
    #pragma unroll
    for (int r=0;r<4;r++){
      int p = rb*64 + ms*16 + quad*4 + r;
      if (p < NPIX){
        float v = fmaxf(acc[ms][r] + bc, 0.f);
        F[((size_t)b*NPIX + p)*64 + col] = v;
        s += v; s2 += v*v;
      }
    }
  #pragma unroll
  for (int o=32;o>0;o>>=1){ s += __shfl_down(s,o); s2 += __shfl_down(s2,o); }
  if (l==0){ red[w]=s; red[4+w]=s2; }
  __syncthreads();
  if (t==0){
    atomicAdd(&stats[b*2],   red[0]+red[1]+red[2]+red[3]);
    atomicAdd(&stats[b*2+1], red[4]+red[5]+red[6]+red[7]);
  }
}

// ---------------------------------------------------------------------------
// K5: LN (no affine) + max over pixels (commutes: rs>0) + lin2 + elu.
// ---------------------------------------------------------------------------
__global__ __launch_bounds__(256) void k_final(
    const float* __restrict__ F, const float* __restrict__ stats,
    const float* __restrict__ w2, const float* __restrict__ b2v,
    float* __restrict__ out)
{
  __shared__ float cm[256];
  __shared__ float nm[64];
  const int b = blockIdx.x, t = threadIdx.x;
  const int d = t&63, grp = t>>6;
  const float* Fb = F + (size_t)b*NPIX*64;
  float m = -1e30f;
  for (int p=grp;p<NPIX;p+=4) m = fmaxf(m, Fb[p*64+d]);
  cm[t]=m;
  __syncthreads();
  if (t<64){
    float mm = fmaxf(fmaxf(cm[t],cm[t+64]), fmaxf(cm[t+128],cm[t+192]));
    const float n = (float)(NPIX*64);
    float S = stats[b*2], S2 = stats[b*2+1];
    float mu = S/n, var = S2/n - mu*mu;
    nm[t] = (mm - mu) * rsqrtf(var + 1e-5f);
  }
  __syncthreads();
  if (t<10){
    float acc = b2v[t];
    for (int e=0;e<64;e++) acc += nm[e]*w2[e*10+t];
    out[b*10+t] = eluf(acc);
  }
}

// ---------------------------------------------------------------------------
extern "C" void kernel_launch(void* const* d_in, const int* in_sizes, int n_in,
                              void* d_out, int out_size, void* d_ws, size_t ws_size,
                              hipStream_t stream)
{
  const float* x       = (const float*)d_in[0];
  const float* conv1_w = (const float*)d_in[1];
  const float* conv1_b = (const float*)d_in[2];
  const float* conv2_w = (const float*)d_in[3];
  const float* conv2_b = (const float*)d_in[4];
  const float* kp_w    = (const float*)d_in[5];
  const float* kp_b    = (const float*)d_in[6];
  const float* qp_w    = (const float*)d_in[7];
  const float* qp_b    = (const float*)d_in[8];
  const float* vp_w    = (const float*)d_in[9];
  const float* vp_b    = (const float*)d_in[10];
  const float* klin_w  = (const float*)d_in[11];
  const float* klin_b  = (const float*)d_in[12];
  const float* qlin_w  = (const float*)d_in[13];
  const float* qlin_b  = (const float*)d_in[14];
  const float* alin_w  = (const float*)d_in[15];
  const float* alin_b  = (const float*)d_in[16];
  const float* knorm_g = (const float*)d_in[17];
  const float* knorm_b = (const float*)d_in[18];
  const float* qnorm_g = (const float*)d_in[19];
  const float* qnorm_b = (const float*)d_in[20];
  const float* vnorm_g = (const float*)d_in[21];
  const float* vnorm_b = (const float*)d_in[22];
  const float* lin1_w  = (const float*)d_in[23];
  const float* lin1_b  = (const float*)d_in[24];
  const float* lin2_w  = (const float*)d_in[25];
  const float* lin2_b  = (const float*)d_in[26];

  // workspace layout
  float* feats  = (float*)d_ws;                         // 1,296,896 f
  float* F      = feats + (size_t)BATCH*NPIX*CH;        // 2,441,216 f
  float* statsE = F + (size_t)BATCH*NPIX*64;            // 128 f
  float* statsP = statsE + 128;                         // 384 f
  ushort* Qb    = (ushort*)(statsP + 384);              // 9,764,864 hw each
  ushort* Kb    = Qb + (size_t)BATCH*4*NPIX*64;
  ushort* Vb    = Kb + (size_t)BATCH*4*NPIX*64;
  ushort* Ew    = Vb + (size_t)BATCH*4*NPIX*64;         // 9,764,864 hw
  ushort* w1T   = Ew + (size_t)BATCH*NPIX*256;          // 16,384 hw
  ushort* alinP = w1T + 16384;                          // 389,120 hw
  ushort* WqkP  = alinP + 389120;                       // 81,920 hw
  ushort* VP    = WqkP + 81920;                         // 9,961,472 hw

  k_conv_feats<<<BATCH, 256, 0, stream>>>(x, conv1_w, conv1_b, conv2_w, conv2_b, feats);

  k_prep<<<238, 256, 0, stream>>>(alin_w, qlin_w, klin_w, lin1_w, alinP, WqkP, w1T, statsE);

  dim3 gp(4, BATCH, 3);
  k_proj_p1<<<gp, 256, 0, stream>>>(feats, kp_w, kp_b, qp_w, qp_b, vp_w, vp_b, statsP);
  k_proj_p2<<<gp, 256, 0, stream>>>(feats, kp_w, kp_b, qp_w, qp_b, vp_w, vp_b,
                                    knorm_g, knorm_b, qnorm_g, qnorm_b, vnorm_g, vnorm_b,
                                    statsP, Kb, Qb, Vb);

  static bool attr_set = false;
  if (!attr_set){
    hipFuncSetAttribute((const void*)k_vt,   hipFuncAttributeMaxDynamicSharedMemorySize, 77824);
    hipFuncSetAttribute((const void*)k_attn, hipFuncAttributeMaxDynamicSharedMemorySize, 161792);
    attr_set = true;
  }
  k_vt<<<BATCH*4, 256, 77824, stream>>>(Vb, VP);

  dim3 ga(5, BATCH*4);
  k_attn<<<ga, 512, 161792, stream>>>(Qb, Kb, alinP, WqkP, VP,
                                      qlin_b, klin_b, alin_b, Ew);

  dim3 gl(10, BATCH);
  k_lin1<<<gl, 256, 0, stream>>>(Ew, w1T, lin1_b, F, statsE);

  k_final<<<BATCH, 256, 0, stream>>>(F, statsE, lin2_w, lin2_b, (float*)d_out);
}

// Round 8
// 705.843 us; speedup vs baseline: 1.1640x; 1.1640x over previous
//
#include <hip/hip_runtime.h>
#include <hip/hip_bf16.h>
#include <math.h>

typedef __hip_bfloat16 bf16;
typedef unsigned short ushort;
typedef __attribute__((ext_vector_type(8))) short short8;
typedef __attribute__((ext_vector_type(4))) float float4v;

#define BATCH 64
#define NPIX 596
#define CH 34
#define PC 256

static __device__ __forceinline__ ushort f2bu(float v){ bf16 h = __float2bfloat16(v); return *(ushort*)&h; }
static __device__ __forceinline__ float eluf(float x){ return x > 0.f ? x : expm1f(x); }

// ---------------------------------------------------------------------------
// K_setup: blocks 0..63 -> conv1+relu->conv2+relu->feats; blocks 64.. -> pack
// weights into MFMA B-fragment order (alinP/WqkP/w1T) + zero stats.
// ---------------------------------------------------------------------------
__global__ __launch_bounds__(256) void k_setup(
    const float* __restrict__ x,
    const float* __restrict__ w1, const float* __restrict__ b1,
    const float* __restrict__ w2, const float* __restrict__ b2,
    float* __restrict__ feats,
    const float* __restrict__ aw, const float* __restrict__ qw, const float* __restrict__ kw,
    const float* __restrict__ l1w,
    ushort* __restrict__ alinP, ushort* __restrict__ WqkP, ushort* __restrict__ w1T,
    float* __restrict__ statsZ)
{
  const int t = threadIdx.x;
  if (blockIdx.x < 64){
    __shared__ float sw1[256];
    __shared__ float sb1[16];
    __shared__ float sw2[2048];
    __shared__ float sb2[32];
    __shared__ float h1[16*150*5];
    const int b = blockIdx.x;
    const float* xb = x + (size_t)b * 4*151*6;

    sw1[t]=w1[t];
    if (t<16) sb1[t]=b1[t];
    for (int i=t;i<2048;i+=256) sw2[i]=w2[i];
    if (t<32) sb2[t]=b2[t];
    __syncthreads();

    for (int i=t;i<12000;i+=256){
      int oc = i/750, rem = i-oc*750;
      int r = rem/5, cc = rem-(rem/5)*5;
      float acc = sb1[oc];
      #pragma unroll
      for (int ic=0;ic<4;ic++){
        const float* xp = xb + ic*906 + r*6 + cc;
        const float* wp = sw1 + oc*16 + ic*4;
        acc += xp[0]*wp[0] + xp[1]*wp[1] + xp[6]*wp[2] + xp[7]*wp[3];
      }
      h1[i] = fmaxf(acc, 0.f);
    }
    __syncthreads();

    float* fb = feats + (size_t)b*NPIX*CH;
    for (int i=t;i<32*NPIX;i+=256){
      int oc = i/NPIX, p = i - oc*NPIX;
      int r = p>>2, cc = p&3;
      float acc = sb2[oc];
      #pragma unroll
      for (int ic=0;ic<16;ic++){
        const float* hp = h1 + ic*750 + r*5 + cc;
        const float* wp = sw2 + oc*64 + ic*4;
        acc += hp[0]*wp[0] + hp[1]*wp[1] + hp[5]*wp[2] + hp[6]*wp[3];
      }
      fb[p*CH+oc] = fmaxf(acc, 0.f);
    }
    for (int p=t;p<NPIX;p+=256){
      fb[p*CH+32] = (float)(p&3)*0.25f;
      fb[p*CH+33] = (float)(p>>2)*(1.0f/149.0f);
    }
    return;
  }
  // ---- prep part ----
  if (blockIdx.x == 64){
    statsZ[t] = 0.f;
    statsZ[t + 256] = 0.f;
  }
  int s = (blockIdx.x-64)*256 + t;
  if (s < 48640){
    int tile = s/(19*64), rem = s%(19*64);
    int kk = rem>>6, l = rem&63;
    int n = tile*16 + (l&15);
    int c0 = kk*32 + (l>>4)*8;
    ushort out[8];
    #pragma unroll
    for (int i=0;i<8;i++){
      int c = c0+i;
      out[i] = (n<NPIX && c<NPIX) ? f2bu(aw[(size_t)c*NPIX + n]) : 0;
    }
    *(short8*)(alinP + (size_t)s*8) = *(short8*)out;
  } else if (s < 58880){
    int s2 = s - 48640;
    int tile = s2/(4*64), rem = s2%(4*64);
    int kk = rem>>6, l = rem&63;
    int n = tile*16 + (l&15);
    int k0 = kk*32 + (l>>4)*8;
    ushort out[8];
    #pragma unroll
    for (int i=0;i<8;i++){
      int k = k0+i;
      float v = 0.f;
      if (n<NPIX) v = (k<64) ? qw[(size_t)k*NPIX + n] : kw[(size_t)(k-64)*NPIX + n];
      out[i] = (n<NPIX) ? f2bu(v) : 0;
    }
    *(short8*)(WqkP + (size_t)s2*8) = *(short8*)out;
  } else if (s < 60928){
    int s3 = s - 58880;
    int n = s3>>5, e0 = (s3&31)*8;
    ushort out[8];
    #pragma unroll
    for (int i=0;i<8;i++) out[i] = f2bu(l1w[(size_t)(e0+i)*64 + n]);
    *(short8*)(w1T + (size_t)s3*8) = *(short8*)out;
  }
}

// ---------------------------------------------------------------------------
// K_vt: pack V into fragment order. Per bh: VP slot g=(w*19+kk)*64+l holds
// V[j = kk*32 + quad*8 + jj][d = w*16 + ln].  4864 short8 per bh.
// ---------------------------------------------------------------------------
__global__ __launch_bounds__(256) void k_vt(
    const ushort* __restrict__ Vb, ushort* __restrict__ VP)
{
  extern __shared__ ushort vt[];     // 64 x 608
  const int bh = blockIdx.x, t = threadIdx.x;
  const ushort* Vp = Vb + (size_t)bh*NPIX*64;
  for (int g=t; g<4768; g+=256){
    int p = g>>3, d0 = (g&7)*8;
    short8 vv = *(const short8*)(Vp + (size_t)p*64 + d0);
    #pragma unroll
    for (int i=0;i<8;i++) vt[(d0+i)*608 + p] = ((ushort*)&vv)[i];
  }
  __syncthreads();
  for (int g=t; g<4864; g+=256){
    int w2 = g/1216, rem = g%1216;
    int kk = rem>>6, l = rem&63;
    int d = w2*16 + (l&15);
    int j0 = kk*32 + (l>>4)*8;
    ushort out[8];
    #pragma unroll
    for (int i=0;i<8;i++){
      int j = j0+i;
      out[i] = (j<NPIX) ? vt[d*608 + j] : 0;
    }
    *(short8*)(VP + ((size_t)bh*4864 + g)*8) = *(short8*)out;
  }
}

// ---------------------------------------------------------------------------
// P1: proj stats. grid (4 ptiles, 64 b, 3 which). atomic partial sums.
// ---------------------------------------------------------------------------
__global__ __launch_bounds__(256) void k_proj_p1(
    const float* __restrict__ feats,
    const float* __restrict__ kpw, const float* __restrict__ kpb,
    const float* __restrict__ qpw, const float* __restrict__ qpb,
    const float* __restrict__ vpw, const float* __restrict__ vpb,
    float* __restrict__ statsP)
{
  __shared__ float sw[CH*PC];
  __shared__ float sb[PC];
  __shared__ float sf[149*CH];
  __shared__ float red[8];
  const int pt = blockIdx.x, b = blockIdx.y, which = blockIdx.z, t = threadIdx.x;
  const float* W  = which==0 ? kpw : which==1 ? qpw : vpw;
  const float* Bv = which==0 ? kpb : which==1 ? qpb : vpb;
  for (int i=t;i<CH*PC;i+=256) sw[i]=W[i];
  sb[t]=Bv[t];
  const float* fb = feats + ((size_t)b*NPIX + pt*149)*CH;
  for (int i=t;i<149*CH;i+=256) sf[i]=fb[i];
  __syncthreads();
  float s=0.f, s2=0.f;
  for (int p=0;p<149;p++){
    float acc = sb[t];
    const float* fr = sf + p*CH;
    #pragma unroll
    for (int e=0;e<CH;e++) acc += fr[e]*sw[e*PC+t];
    s += acc; s2 += acc*acc;
  }
  #pragma unroll
  for (int o=32;o>0;o>>=1){ s += __shfl_down(s,o); s2 += __shfl_down(s2,o); }
  if ((t&63)==0){ red[t>>6]=s; red[4+(t>>6)]=s2; }
  __syncthreads();
  if (t==0){
    atomicAdd(&statsP[(which*64+b)*2],   red[0]+red[1]+red[2]+red[3]);
    atomicAdd(&statsP[(which*64+b)*2+1], red[4]+red[5]+red[6]+red[7]);
  }
}

// ---------------------------------------------------------------------------
// P2: proj recompute + LN + affine -> bf16 (B,4,596,64).
// ---------------------------------------------------------------------------
__global__ __launch_bounds__(256) void k_proj_p2(
    const float* __restrict__ feats,
    const float* __restrict__ kpw, const float* __restrict__ kpb,
    const float* __restrict__ qpw, const float* __restrict__ qpb,
    const float* __restrict__ vpw, const float* __restrict__ vpb,
    const float* __restrict__ kg, const float* __restrict__ kb_,
    const float* __restrict__ qg, const float* __restrict__ qb_,
    const float* __restrict__ vg, const float* __restrict__ vb_,
    const float* __restrict__ statsP,
    ushort* __restrict__ Kb, ushort* __restrict__ Qb, ushort* __restrict__ Vb)
{
  __shared__ float sw[CH*PC];
  __shared__ float sb[PC];
  __shared__ float sf[149*CH];
  const int pt = blockIdx.x, b = blockIdx.y, which = blockIdx.z, t = threadIdx.x;
  const float* W  = which==0 ? kpw : which==1 ? qpw : vpw;
  const float* Bv = which==0 ? kpb : which==1 ? qpb : vpb;
  const float* G  = which==0 ? kg  : which==1 ? qg  : vg;
  const float* Be = which==0 ? kb_ : which==1 ? qb_ : vb_;
  ushort* out     = which==0 ? Kb  : which==1 ? Qb  : Vb;
  for (int i=t;i<CH*PC;i+=256) sw[i]=W[i];
  sb[t]=Bv[t];
  const float* fb = feats + ((size_t)b*NPIX + pt*149)*CH;
  for (int i=t;i<149*CH;i+=256) sf[i]=fb[i];
  __syncthreads();
  const float n = (float)(NPIX*PC);
  const float S  = statsP[(which*64+b)*2];
  const float S2 = statsP[(which*64+b)*2+1];
  const float mu = S/n;
  const float rs = rsqrtf(S2/n - mu*mu + 1e-5f);
  const int h = t>>6, d = t&63;
  for (int p=0;p<149;p++){
    float acc = sb[t];
    const float* fr = sf + p*CH;
    #pragma unroll
    for (int e=0;e<CH;e++) acc += fr[e]*sw[e*PC+t];
    int pg = pt*149 + p;
    int gi = (h*NPIX+pg)*64 + d;
    float y = (acc-mu)*rs*G[gi] + Be[gi];
    out[((size_t)(b*4+h)*NPIX + pg)*64 + d] = f2bu(y);
  }
}

// ---------------------------------------------------------------------------
// K3: fused MFMA attention (r5 tiling). M=64 rows/block, N=640 (40 tiles),
// 256 threads (4 waves x 10 n-tiles). B-frags stream from global packed
// buffers; A-frags from LDS strip. red scoreboard lives in strip col-tail
// (608..615). LDS = 78,848 B -> 2 blocks/CU. grid (10 row-strips, 256 bh).
// ---------------------------------------------------------------------------
__global__ __launch_bounds__(256, 2) void k_attn(
    const ushort* __restrict__ Qb, const ushort* __restrict__ Kb,
    const ushort* __restrict__ alinP, const ushort* __restrict__ WqkP,
    const ushort* __restrict__ VP,
    const float* __restrict__ qbias, const float* __restrict__ kbias,
    const float* __restrict__ abias,
    ushort* __restrict__ Ew)
{
  extern __shared__ __align__(16) ushort sm[];
  ushort* strip = sm;                    // 64*616 halves = 78,848 B

  const int t = threadIdx.x;
  const int w = t>>6, l = t&63, quad = l>>4, ln = l&15;
  const int rb = blockIdx.x, bh = blockIdx.y;
  const int b = bh>>2, h = bh&3;
  const int row0 = rb*64;
  const ushort* Qp = Qb + (size_t)bh*NPIX*64;
  const ushort* Kp = Kb + (size_t)bh*NPIX*64;

  // red scoreboard: 4 f32 per row in strip tail halves [608..615]
  auto redp = [&](int row)->float* { return (float*)(strip + row*616 + 608); };

  float4v acc[4][10];
  #pragma unroll
  for (int ms=0;ms<4;ms++)
    #pragma unroll
    for (int i=0;i<10;i++) acc[ms][i] = (float4v){0.f,0.f,0.f,0.f};

  // ---------------- A0 = elu([Q|K] @ Wqk + qb + kb) ----------------
  #pragma unroll
  for (int kk=0;kk<4;kk++){
    short8 aq[4];
    #pragma unroll
    for (int ms=0;ms<4;ms++){
      int r = row0 + ms*16 + ln;
      short8 z = {0,0,0,0,0,0,0,0};
      aq[ms] = (r < NPIX)
        ? *(const short8*)((kk<2 ? Qp : Kp) + (size_t)r*64 + (kk&1)*32 + quad*8) : z;
    }
    #pragma unroll
    for (int i=0;i<10;i++){
      int tile = w + 4*i;
      short8 bf = *(const short8*)(WqkP + ((size_t)(tile*4 + kk)*64 + l)*8);
      #pragma unroll
      for (int ms=0;ms<4;ms++)
        acc[ms][i] = __builtin_amdgcn_mfma_f32_16x16x32_bf16(aq[ms], bf, acc[ms][i], 0,0,0);
    }
  }
  // epilogue: bias + elu -> strip
  #pragma unroll
  for (int i=0;i<10;i++){
    int t0 = w + 4*i;
    if (t0 < 38){
      int col = t0*16 + ln;
      bool cv = col < NPIX;
      float qkb = cv ? (qbias[col] + kbias[col]) : 0.f;
      #pragma unroll
      for (int ms=0;ms<4;ms++)
        #pragma unroll
        for (int r=0;r<4;r++){
          float v = 0.f;
          if (cv){ float xx = acc[ms][i][r] + qkb; v = xx > 0.f ? xx : __expf(xx) - 1.f; }
          strip[(ms*16+quad*4+r)*616 + col] = f2bu(v);
        }
    }
  }
  __syncthreads();

  // ---------------- S = A0 @ alin (no barriers in loop) ----------------
  #pragma unroll
  for (int ms=0;ms<4;ms++)
    #pragma unroll
    for (int i=0;i<10;i++) acc[ms][i] = (float4v){0.f,0.f,0.f,0.f};
  for (int kk=0;kk<19;kk++){
    short8 af[4];
    #pragma unroll
    for (int ms=0;ms<4;ms++)
      af[ms] = *(const short8*)(strip + (ms*16+ln)*616 + kk*32 + quad*8);
    #pragma unroll
    for (int i=0;i<10;i++){
      int tile = w + 4*i;
      short8 bf = *(const short8*)(alinP + ((size_t)(tile*19 + kk)*64 + l)*8);
      #pragma unroll
      for (int ms=0;ms<4;ms++)
        acc[ms][i] = __builtin_amdgcn_mfma_f32_16x16x32_bf16(af[ms], bf, acc[ms][i], 0,0,0);
    }
  }

  // ---------------- softmax (exact, cross-wave over 4 waves) ----------------
  float M_[4][4], sum[4][4], inv[4][4];
  #pragma unroll
  for (int ms=0;ms<4;ms++)
    #pragma unroll
    for (int r=0;r<4;r++) M_[ms][r] = -1e30f;
  #pragma unroll
  for (int i=0;i<10;i++){
    int col = (w+4*i)*16 + ln;
    float ab = (col < NPIX) ? abias[col] : 0.f;
    #pragma unroll
    for (int ms=0;ms<4;ms++)
      #pragma unroll
      for (int r=0;r<4;r++){
        float s = (col < NPIX) ? acc[ms][i][r] + ab : -1e30f;
        acc[ms][i][r] = s;
        M_[ms][r] = fmaxf(M_[ms][r], s);
      }
  }
  #pragma unroll
  for (int ms=0;ms<4;ms++)
    #pragma unroll
    for (int r=0;r<4;r++)
      #pragma unroll
      for (int o=8;o>0;o>>=1) M_[ms][r] = fmaxf(M_[ms][r], __shfl_xor(M_[ms][r], o, 16));
  __syncthreads();   // strip A0 reads done; tail safe to write
  if (ln==0){
    #pragma unroll
    for (int ms=0;ms<4;ms++)
      #pragma unroll
      for (int r=0;r<4;r++) redp(ms*16+quad*4+r)[w] = M_[ms][r];
  }
  __syncthreads();
  #pragma unroll
  for (int ms=0;ms<4;ms++)
    #pragma unroll
    for (int r=0;r<4;r++){
      const float* rr = redp(ms*16+quad*4+r);
      M_[ms][r] = fmaxf(fmaxf(rr[0],rr[1]), fmaxf(rr[2],rr[3]));
      sum[ms][r] = 0.f;
    }
  #pragma unroll
  for (int i=0;i<10;i++)
    #pragma unroll
    for (int ms=0;ms<4;ms++)
      #pragma unroll
      for (int r=0;r<4;r++){
        float e = __expf(acc[ms][i][r] - M_[ms][r]);
        acc[ms][i][r] = e;
        sum[ms][r] += e;
      }
  #pragma unroll
  for (int ms=0;ms<4;ms++)
    #pragma unroll
    for (int r=0;r<4;r++)
      #pragma unroll
      for (int o=8;o>0;o>>=1) sum[ms][r] += __shfl_xor(sum[ms][r], o, 16);
  __syncthreads();
  if (ln==0){
    #pragma unroll
    for (int ms=0;ms<4;ms++)
      #pragma unroll
      for (int r=0;r<4;r++) redp(ms*16+quad*4+r)[w] = sum[ms][r];
  }
  __syncthreads();
  #pragma unroll
  for (int ms=0;ms<4;ms++)
    #pragma unroll
    for (int r=0;r<4;r++){
      const float* rr = redp(ms*16+quad*4+r);
      inv[ms][r] = 1.f / (rr[0]+rr[1]+rr[2]+rr[3]);
    }
  #pragma unroll
  for (int i=0;i<10;i++){
    int t0 = w + 4*i;
    if (t0 < 38){
      int col = t0*16 + ln;
      #pragma unroll
      for (int ms=0;ms<4;ms++)
        #pragma unroll
        for (int r=0;r<4;r++)
          strip[(ms*16+quad*4+r)*616 + col] = f2bu(acc[ms][i][r] * inv[ms][r]);
    }
  }
  __syncthreads();

  // ---------------- E = P @ V  (wave w = d-tile) ----------------
  float4v ve[4];
  #pragma unroll
  for (int ms=0;ms<4;ms++) ve[ms] = (float4v){0.f,0.f,0.f,0.f};
  for (int kk=0;kk<19;kk++){
    short8 bf = *(const short8*)(VP + ((size_t)bh*4864 + (w*19 + kk)*64 + l)*8);
    #pragma unroll
    for (int ms=0;ms<4;ms++){
      short8 af = *(const short8*)(strip + (ms*16+ln)*616 + kk*32 + quad*8);
      ve[ms] = __builtin_amdgcn_mfma_f32_16x16x32_bf16(af, bf, ve[ms], 0,0,0);
    }
  }
  __syncthreads();   // all strip reads done
  // stage 64x64 bf16 tile (row stride 72 halves) for coalesced Ew write
  #pragma unroll
  for (int ms=0;ms<4;ms++)
    #pragma unroll
    for (int r=0;r<4;r++)
      strip[(ms*16+quad*4+r)*72 + w*16 + ln] = f2bu(ve[ms][r]);
  __syncthreads();
  {
    int p = t>>2, seg = t&3;
    int gp = row0 + p;
    if (gp < NPIX){
      short8 v0 = *(const short8*)(strip + p*72 + seg*16);
      short8 v1 = *(const short8*)(strip + p*72 + seg*16 + 8);
      ushort* dst = Ew + ((size_t)b*NPIX + gp)*256 + h*64 + seg*16;
      *(short8*)dst = v0;
      *(short8*)(dst + 8) = v1;
    }
  }
}

// ---------------------------------------------------------------------------
// K4: lin1 via MFMA + relu + per-batch LN stats. grid (10 rowblocks, 64 b).
// ---------------------------------------------------------------------------
__global__ __launch_bounds__(256) void k_lin1(
    const ushort* __restrict__ Ew, const ushort* __restrict__ w1T,
    const float* __restrict__ bias,
    float* __restrict__ F, float* __restrict__ stats)
{
  __shared__ ushort sw1[64*264];
  __shared__ float red[8];
  const int t = threadIdx.x;
  const int w = t>>6, l = t&63, quad = l>>4, ln = l&15;
  const int rb = blockIdx.x, b = blockIdx.y;
  for (int g=t; g<2048; g+=256){
    int row = g>>5, q = g&31;
    *(short8*)(sw1 + row*264 + q*8) = *(const short8*)(w1T + row*256 + q*8);
  }
  __syncthreads();
  float4v acc[4];
  #pragma unroll
  for (int ms=0;ms<4;ms++) acc[ms] = (float4v){0.f,0.f,0.f,0.f};
  #pragma unroll
  for (int kk=0;kk<8;kk++){
    short8 bf = *(const short8*)(sw1 + (w*16+ln)*264 + kk*32 + quad*8);
    #pragma unroll
    for (int ms=0;ms<4;ms++){
      int p = rb*64 + ms*16 + ln;
      size_t rowi = (size_t)b*NPIX + (p < NPIX ? p : 0);
      short8 a = *(const short8*)(Ew + rowi*256 + kk*32 + quad*8);
      acc[ms] = __builtin_amdgcn_mfma_f32_16x16x32_bf16(a, bf, acc[ms], 0,0,0);
    }
  }
  const int col = w*16 + ln;
  const float bc = bias[col];
  float s=0.f, s2=0.f;
  #pragma unroll
  for (int ms=0;ms<4;ms++)
    #pragma unroll
    for (int r=0;r<4;r++){
      int p = rb*64 + ms*16 + quad*4 + r;
      if (p < NPIX){
        float v = fmaxf(acc[ms][r] + bc, 0.f);
        F[((size_t)b*NPIX + p)*64 + col] = v;
        s += v; s2 += v*v;
      }
    }
  #pragma unroll
  for (int o=32;o>0;o>>=1){ s += __shfl_down(s,o); s2 += __shfl_down(s2,o); }
  if (l==0){ red[w]=s; red[4+w]=s2; }
  __syncthreads();
  if (t==0){
    atomicAdd(&stats[b*2],   red[0]+red[1]+red[2]+red[3]);
    atomicAdd(&stats[b*2+1], red[4]+red[5]+red[6]+red[7]);
  }
}

// ---------------------------------------------------------------------------
// K5: LN (no affine) + max over pixels (commutes: rs>0) + lin2 + elu.
// ---------------------------------------------------------------------------
__global__ __launch_bounds__(256) void k_final(
    const float* __restrict__ F, const float* __restrict__ stats,
    const float* __restrict__ w2, const float* __restrict__ b2v,
    float* __restrict__ out)
{
  __shared__ float cm[256];
  __shared__ float nm[64];
  const int b = blockIdx.x, t = threadIdx.x;
  const int d = t&63, grp = t>>6;
  const float* Fb = F + (size_t)b*NPIX*64;
  float m = -1e30f;
  for (int p=grp;p<NPIX;p+=4) m = fmaxf(m, Fb[p*64+d]);
  cm[t]=m;
  __syncthreads();
  if (t<64){
    float mm = fmaxf(fmaxf(cm[t],cm[t+64]), fmaxf(cm[t+128],cm[t+192]));
    const float n = (float)(NPIX*64);
    float S = stats[b*2], S2 = stats[b*2+1];
    float mu = S/n, var = S2/n - mu*mu;
    nm[t] = (mm - mu) * rsqrtf(var + 1e-5f);
  }
  __syncthreads();
  if (t<10){
    float acc = b2v[t];
    for (int e=0;e<64;e++) acc += nm[e]*w2[e*10+t];
    out[b*10+t] = eluf(acc);
  }
}

// ---------------------------------------------------------------------------
extern "C" void kernel_launch(void* const* d_in, const int* in_sizes, int n_in,
                              void* d_out, int out_size, void* d_ws, size_t ws_size,
                              hipStream_t stream)
{
  const float* x       = (const float*)d_in[0];
  const float* conv1_w = (const float*)d_in[1];
  const float* conv1_b = (const float*)d_in[2];
  const float* conv2_w = (const float*)d_in[3];
  const float* conv2_b = (const float*)d_in[4];
  const float* kp_w    = (const float*)d_in[5];
  const float* kp_b    = (const float*)d_in[6];
  const float* qp_w    = (const float*)d_in[7];
  const float* qp_b    = (const float*)d_in[8];
  const float* vp_w    = (const float*)d_in[9];
  const float* vp_b    = (const float*)d_in[10];
  const float* klin_w  = (const float*)d_in[11];
  const float* klin_b  = (const float*)d_in[12];
  const float* qlin_w  = (const float*)d_in[13];
  const float* qlin_b  = (const float*)d_in[14];
  const float* alin_w  = (const float*)d_in[15];
  const float* alin_b  = (const float*)d_in[16];
  const float* knorm_g = (const float*)d_in[17];
  const float* knorm_b = (const float*)d_in[18];
  const float* qnorm_g = (const float*)d_in[19];
  const float* qnorm_b = (const float*)d_in[20];
  const float* vnorm_g = (const float*)d_in[21];
  const float* vnorm_b = (const float*)d_in[22];
  const float* lin1_w  = (const float*)d_in[23];
  const float* lin1_b  = (const float*)d_in[24];
  const float* lin2_w  = (const float*)d_in[25];
  const float* lin2_b  = (const float*)d_in[26];

  // workspace layout
  float* feats  = (float*)d_ws;                         // 1,296,896 f
  float* F      = feats + (size_t)BATCH*NPIX*CH;        // 2,441,216 f
  float* statsE = F + (size_t)BATCH*NPIX*64;            // 128 f
  float* statsP = statsE + 128;                         // 384 f
  ushort* Qb    = (ushort*)(statsP + 384);              // 9,764,864 hw each
  ushort* Kb    = Qb + (size_t)BATCH*4*NPIX*64;
  ushort* Vb    = Kb + (size_t)BATCH*4*NPIX*64;
  ushort* Ew    = Vb + (size_t)BATCH*4*NPIX*64;         // 9,764,864 hw
  ushort* w1T   = Ew + (size_t)BATCH*NPIX*256;          // 16,384 hw
  ushort* alinP = w1T + 16384;                          // 389,120 hw
  ushort* WqkP  = alinP + 389120;                       // 81,920 hw
  ushort* VP    = WqkP + 81920;                         // 9,961,472 hw

  k_setup<<<302, 256, 0, stream>>>(x, conv1_w, conv1_b, conv2_w, conv2_b, feats,
                                   alin_w, qlin_w, klin_w, lin1_w,
                                   alinP, WqkP, w1T, statsE);

  dim3 gp(4, BATCH, 3);
  k_proj_p1<<<gp, 256, 0, stream>>>(feats, kp_w, kp_b, qp_w, qp_b, vp_w, vp_b, statsP);
  k_proj_p2<<<gp, 256, 0, stream>>>(feats, kp_w, kp_b, qp_w, qp_b, vp_w, vp_b,
                                    knorm_g, knorm_b, qnorm_g, qnorm_b, vnorm_g, vnorm_b,
                                    statsP, Kb, Qb, Vb);

  static bool attr_set = false;
  if (!attr_set){
    hipFuncSetAttribute((const void*)k_vt,   hipFuncAttributeMaxDynamicSharedMemorySize, 77824);
    hipFuncSetAttribute((const void*)k_attn, hipFuncAttributeMaxDynamicSharedMemorySize, 78848);
    attr_set = true;
  }
  k_vt<<<BATCH*4, 256, 77824, stream>>>(Vb, VP);

  dim3 ga(10, BATCH*4);
  k_attn<<<ga, 256, 78848, stream>>>(Qb, Kb, alinP, WqkP, VP,
                                     qlin_b, klin_b, alin_b, Ew);

  dim3 gl(10, BATCH);
  k_lin1<<<gl, 256, 0, stream>>>(Ew, w1T, lin1_b, F, statsE);

  k_final<<<BATCH, 256, 0, stream>>>(F, statsE, lin2_w, lin2_b, (float*)d_out);
}